// Round 1
// baseline (1783.706 us; speedup 1.0000x reference)
//
#include <hip/hip_runtime.h>
#include <stdint.h>

typedef unsigned short u16;
typedef unsigned int u32;
typedef __attribute__((ext_vector_type(4))) float f32x4;
typedef __attribute__((ext_vector_type(8))) short s16x8;

__device__ __forceinline__ u16 f2bf(float f) {
  u32 u = __builtin_bit_cast(u32, f);
  u += 0x7fffu + ((u >> 16) & 1u);
  return (u16)(u >> 16);
}
__device__ __forceinline__ float bflo2f(u32 w) {  // bf16 in low 16 bits
  return __builtin_bit_cast(float, w << 16);
}
__device__ __forceinline__ float bfhi2f(u32 w) {  // bf16 in high 16 bits
  return __builtin_bit_cast(float, w & 0xffff0000u);
}

// ---------------------------------------------------------------------------
// Tiled transpose fp32 -> bf16: dst[(c)*dstStride + r] = src[r*Ccols + c]
// grid: (Ccols/64, R/64, Z). Per z: src += srcZ, dst += dstZ.
// ---------------------------------------------------------------------------
__global__ __launch_bounds__(256) void transpose_f32_bf16(
    const float* __restrict__ src, u16* __restrict__ dst,
    int Ccols, long srcZ, long dstZ, int dstStride) {
  __shared__ float t[64][65];
  const float* s = src + (size_t)blockIdx.z * srcZ;
  u16* d = dst + (size_t)blockIdx.z * dstZ;
  const int r0 = blockIdx.y * 64, c0 = blockIdx.x * 64;
  const int tr = threadIdx.x >> 4, tc4 = (threadIdx.x & 15) * 4;
#pragma unroll
  for (int p = 0; p < 4; ++p) {
    int r = p * 16 + tr;
    float4 v = *(const float4*)(s + (size_t)(r0 + r) * Ccols + c0 + tc4);
    t[r][tc4 + 0] = v.x; t[r][tc4 + 1] = v.y;
    t[r][tc4 + 2] = v.z; t[r][tc4 + 3] = v.w;
  }
  __syncthreads();
#pragma unroll
  for (int p = 0; p < 4; ++p) {
    int c = p * 16 + tr;
    uint2 pk;
    pk.x = (u32)f2bf(t[tc4 + 0][c]) | ((u32)f2bf(t[tc4 + 1][c]) << 16);
    pk.y = (u32)f2bf(t[tc4 + 2][c]) | ((u32)f2bf(t[tc4 + 3][c]) << 16);
    *(uint2*)(d + (size_t)(c0 + c) * dstStride + r0 + tc4) = pk;
  }
}

// ---------------------------------------------------------------------------
// LayerNorm: one block per row of 1024 fp32; out bf16.
// ---------------------------------------------------------------------------
__global__ __launch_bounds__(256) void ln_kernel(
    const float* __restrict__ x, const float* __restrict__ g,
    const float* __restrict__ be, u16* __restrict__ out) {
  const int row = blockIdx.x, tid = threadIdx.x;
  const float* xr = x + (size_t)row * 1024;
  float4 v = *(const float4*)(xr + tid * 4);
  float s = v.x + v.y + v.z + v.w;
  float q = v.x * v.x + v.y * v.y + v.z * v.z + v.w * v.w;
#pragma unroll
  for (int off = 32; off > 0; off >>= 1) {
    s += __shfl_down(s, off);
    q += __shfl_down(q, off);
  }
  __shared__ float red[8];
  const int wid = tid >> 6, lane = tid & 63;
  if (lane == 0) { red[wid] = s; red[wid + 4] = q; }
  __syncthreads();
  s = red[0] + red[1] + red[2] + red[3];
  q = red[4] + red[5] + red[6] + red[7];
  const float mu = s * (1.f / 1024.f);
  const float var = q * (1.f / 1024.f) - mu * mu;
  const float rs = rsqrtf(var + 1e-5f);
  float4 gv = *(const float4*)(g + tid * 4);
  float4 bv = *(const float4*)(be + tid * 4);
  float o0 = (v.x - mu) * rs * gv.x + bv.x;
  float o1 = (v.y - mu) * rs * gv.y + bv.y;
  float o2 = (v.z - mu) * rs * gv.z + bv.z;
  float o3 = (v.w - mu) * rs * gv.w + bv.w;
  uint2 pk;
  pk.x = (u32)f2bf(o0) | ((u32)f2bf(o1) << 16);
  pk.y = (u32)f2bf(o2) | ((u32)f2bf(o3) << 16);
  *(uint2*)(out + (size_t)row * 1024 + tid * 4) = pk;
}

// ---------------------------------------------------------------------------
// GEMM: C[M,N] = A[M,K] @ BT[N,K]^T  (+ bias, relu, residual per EPI)
// EPI 0: -> bf16.  EPI 1: +bias, relu -> bf16.  EPI 2: +bias +resid -> fp32.
// 128x128 tile, BK=64, 256 threads (4 waves, 2x2), mfma 16x16x32 bf16.
// ---------------------------------------------------------------------------
template <int EPI>
__global__ __launch_bounds__(256) void gemm_kernel(
    const u16* __restrict__ A, const u16* __restrict__ BT,
    const float* __restrict__ bias, const float* __restrict__ resid,
    void* __restrict__ out, int M, int N, int K) {
  __shared__ u16 sA[128][72];
  __shared__ u16 sB[128][72];
  const int tid = threadIdx.x;
  const int m0 = blockIdx.y * 128, n0 = blockIdx.x * 128;
  const int wid = tid >> 6, lane = tid & 63;
  const int wr = (wid >> 1) * 64, wc = (wid & 1) * 64;
  const int l15 = lane & 15, l4 = lane >> 4;
  f32x4 acc[4][4] = {};
  const int sr = tid >> 3, sc8 = (tid & 7) * 8;

  for (int k0 = 0; k0 < K; k0 += 64) {
    __syncthreads();
#pragma unroll
    for (int p = 0; p < 4; ++p) {
      int r = p * 32 + sr;
      *(uint4*)(&sA[r][sc8]) = *(const uint4*)(A + (size_t)(m0 + r) * K + k0 + sc8);
      *(uint4*)(&sB[r][sc8]) = *(const uint4*)(BT + (size_t)(n0 + r) * K + k0 + sc8);
    }
    __syncthreads();
#pragma unroll
    for (int kk = 0; kk < 64; kk += 32) {
      s16x8 af[4], bf[4];
#pragma unroll
      for (int m = 0; m < 4; ++m)
        af[m] = *(const s16x8*)(&sA[wr + m * 16 + l15][kk + l4 * 8]);
#pragma unroll
      for (int n = 0; n < 4; ++n)
        bf[n] = *(const s16x8*)(&sB[wc + n * 16 + l15][kk + l4 * 8]);
#pragma unroll
      for (int m = 0; m < 4; ++m)
#pragma unroll
        for (int n = 0; n < 4; ++n)
          acc[m][n] = __builtin_amdgcn_mfma_f32_16x16x32_bf16(af[m], bf[n], acc[m][n], 0, 0, 0);
    }
  }

#pragma unroll
  for (int m = 0; m < 4; ++m) {
#pragma unroll
    for (int n = 0; n < 4; ++n) {
      const int col = n0 + wc + n * 16 + l15;
      float bv = 0.f;
      if (EPI >= 1) bv = bias[col];
#pragma unroll
      for (int i = 0; i < 4; ++i) {
        const int row = m0 + wr + m * 16 + l4 * 4 + i;
        float v = acc[m][n][i];
        if (EPI >= 1) v += bv;
        if (EPI == 1) v = fmaxf(v, 0.f);
        if (EPI == 2) {
          v += resid[(size_t)row * N + col];
          ((float*)out)[(size_t)row * N + col] = v;
        } else {
          ((u16*)out)[(size_t)row * N + col] = f2bf(v);
        }
      }
    }
  }
}

// ---------------------------------------------------------------------------
// Causal flash attention, fp32 compute, thread-per-query.
// qkv: [B*T][3072] bf16, row = q(0..1023) | k(1024..2047) | v(2048..3071),
// per-head cols h*64+d. out o: [B*T][1024] bf16 (heads concatenated).
// grid: (T/64, B*H), block 64 threads.
// ---------------------------------------------------------------------------
__global__ __launch_bounds__(64) void attn_kernel(
    const u16* __restrict__ qkv, u16* __restrict__ o) {
  __shared__ float sK[32][68];
  __shared__ float sV[32][68];
  const int tid = threadIdx.x;
  const int b = blockIdx.y >> 4, h = blockIdx.y & 15;
  const int t = blockIdx.x * 64 + tid;
  const float qs = 0.125f * 1.4426950408889634f;  // scale * log2(e)
  float q[64];
  {
    const u16* qp = qkv + ((size_t)(b * 2048 + t)) * 3072 + h * 64;
#pragma unroll
    for (int i = 0; i < 8; ++i) {
      uint4 v = *(const uint4*)(qp + i * 8);
      q[i * 8 + 0] = bflo2f(v.x & 0xffffu) * qs; q[i * 8 + 1] = bfhi2f(v.x) * qs;
      q[i * 8 + 2] = bflo2f(v.y & 0xffffu) * qs; q[i * 8 + 3] = bfhi2f(v.y) * qs;
      q[i * 8 + 4] = bflo2f(v.z & 0xffffu) * qs; q[i * 8 + 5] = bfhi2f(v.z) * qs;
      q[i * 8 + 6] = bflo2f(v.w & 0xffffu) * qs; q[i * 8 + 7] = bfhi2f(v.w) * qs;
    }
  }
  float oa[64];
#pragma unroll
  for (int d = 0; d < 64; ++d) oa[d] = 0.f;
  float m = -1e30f, l = 0.f;
  const int smax = blockIdx.x * 64 + 63;
  const int krow = tid >> 1, kc = (tid & 1) << 5;

  for (int s0 = 0; s0 <= smax; s0 += 32) {
    __syncthreads();
    const u16* kp = qkv + ((size_t)(b * 2048 + s0 + krow)) * 3072 + 1024 + h * 64 + kc;
#pragma unroll
    for (int i = 0; i < 4; ++i) {
      uint4 kv = *(const uint4*)(kp + i * 8);
      uint4 vv = *(const uint4*)(kp + 1024 + i * 8);
      f32x4 ka, kb, va, vb;
      ka[0] = bflo2f(kv.x & 0xffffu); ka[1] = bfhi2f(kv.x);
      ka[2] = bflo2f(kv.y & 0xffffu); ka[3] = bfhi2f(kv.y);
      kb[0] = bflo2f(kv.z & 0xffffu); kb[1] = bfhi2f(kv.z);
      kb[2] = bflo2f(kv.w & 0xffffu); kb[3] = bfhi2f(kv.w);
      va[0] = bflo2f(vv.x & 0xffffu); va[1] = bfhi2f(vv.x);
      va[2] = bflo2f(vv.y & 0xffffu); va[3] = bfhi2f(vv.y);
      vb[0] = bflo2f(vv.z & 0xffffu); vb[1] = bfhi2f(vv.z);
      vb[2] = bflo2f(vv.w & 0xffffu); vb[3] = bfhi2f(vv.w);
      *(f32x4*)(&sK[krow][kc + i * 8]) = ka;
      *(f32x4*)(&sK[krow][kc + i * 8 + 4]) = kb;
      *(f32x4*)(&sV[krow][kc + i * 8]) = va;
      *(f32x4*)(&sV[krow][kc + i * 8 + 4]) = vb;
    }
    __syncthreads();
    const int send = min(t - s0, 31);
    for (int sl = 0; sl <= send; ++sl) {
      float p0 = 0.f, p1 = 0.f, p2 = 0.f, p3 = 0.f;
#pragma unroll
      for (int d4 = 0; d4 < 16; ++d4) {
        f32x4 kv = *(const f32x4*)(&sK[sl][d4 * 4]);
        p0 += q[d4 * 4 + 0] * kv[0];
        p1 += q[d4 * 4 + 1] * kv[1];
        p2 += q[d4 * 4 + 2] * kv[2];
        p3 += q[d4 * 4 + 3] * kv[3];
      }
      const float scv = (p0 + p1) + (p2 + p3);  // already in log2 domain
      if (scv - m > 12.f) {  // defer-max rescale (T13)
        const float corr = exp2f(m - scv);
        l *= corr;
#pragma unroll
        for (int d = 0; d < 64; ++d) oa[d] *= corr;
        m = scv;
      }
      const float p = exp2f(scv - m);
      l += p;
#pragma unroll
      for (int d4 = 0; d4 < 16; ++d4) {
        f32x4 vv = *(const f32x4*)(&sV[sl][d4 * 4]);
        oa[d4 * 4 + 0] += p * vv[0];
        oa[d4 * 4 + 1] += p * vv[1];
        oa[d4 * 4 + 2] += p * vv[2];
        oa[d4 * 4 + 3] += p * vv[3];
      }
    }
  }
  const float inv = 1.f / l;
  u16* op = o + ((size_t)(b * 2048 + t)) * 1024 + h * 64;
#pragma unroll
  for (int i = 0; i < 16; ++i) {
    uint2 pk;
    pk.x = (u32)f2bf(oa[i * 4 + 0] * inv) | ((u32)f2bf(oa[i * 4 + 1] * inv) << 16);
    pk.y = (u32)f2bf(oa[i * 4 + 2] * inv) | ((u32)f2bf(oa[i * 4 + 3] * inv) << 16);
    *(uint2*)(op + i * 4) = pk;
  }
}

// ---------------------------------------------------------------------------
extern "C" void kernel_launch(void* const* d_in, const int* in_sizes, int n_in,
                              void* d_out, int out_size, void* d_ws, size_t ws_size,
                              hipStream_t stream) {
  const float* x     = (const float*)d_in[0];
  const float* Wq    = (const float*)d_in[1];
  const float* Wk    = (const float*)d_in[2];
  const float* Wv    = (const float*)d_in[3];
  const float* Wproj = (const float*)d_in[4];
  const float* bproj = (const float*)d_in[5];
  const float* W1    = (const float*)d_in[6];
  const float* b1    = (const float*)d_in[7];
  const float* W2    = (const float*)d_in[8];
  const float* b2    = (const float*)d_in[9];
  const float* g1    = (const float*)d_in[10];
  const float* be1   = (const float*)d_in[11];
  const float* g2    = (const float*)d_in[12];
  const float* be2   = (const float*)d_in[13];
  float* out = (float*)d_out;

  // workspace layout (bytes): total = 117,440,512
  u16* WqkvT  = (u16*)d_ws;                    // [3072][1024] bf16
  u16* WprojT = WqkvT + (size_t)3072 * 1024;   // [1024][1024]
  u16* W1T    = WprojT + (size_t)1024 * 1024;  // [4096][1024]
  u16* W2T    = W1T + (size_t)4096 * 1024;     // [1024][4096]
  u16* hbuf   = W2T + (size_t)1024 * 4096;     // [4096][1024]
  u16* qkv    = hbuf + (size_t)4096 * 1024;    // [4096][3072]
  u16* obuf   = qkv + (size_t)4096 * 3072;     // [4096][1024]
  float* x2   = (float*)(obuf + (size_t)4096 * 1024);  // [4096][1024] fp32
  u16* a1     = (u16*)(x2 + (size_t)4096 * 1024);      // [4096][4096]

  // weight prep: fp32 -> bf16 transposed
  transpose_f32_bf16<<<dim3(1, 16, 16), 256, 0, stream>>>(Wq, WqkvT,                      64, 65536, 65536, 1024);
  transpose_f32_bf16<<<dim3(1, 16, 16), 256, 0, stream>>>(Wk, WqkvT + (size_t)1024 * 1024, 64, 65536, 65536, 1024);
  transpose_f32_bf16<<<dim3(1, 16, 16), 256, 0, stream>>>(Wv, WqkvT + (size_t)2048 * 1024, 64, 65536, 65536, 1024);
  transpose_f32_bf16<<<dim3(16, 16, 1), 256, 0, stream>>>(Wproj, WprojT, 1024, 0, 0, 1024);
  transpose_f32_bf16<<<dim3(64, 16, 1), 256, 0, stream>>>(W1, W1T, 4096, 0, 0, 1024);
  transpose_f32_bf16<<<dim3(16, 64, 1), 256, 0, stream>>>(W2, W2T, 1024, 0, 0, 4096);

  // h = LN1(x)
  ln_kernel<<<4096, 256, 0, stream>>>(x, g1, be1, hbuf);
  // qkv = h @ WqkvT^T
  gemm_kernel<0><<<dim3(24, 32), 256, 0, stream>>>(hbuf, WqkvT, nullptr, nullptr, qkv, 4096, 3072, 1024);
  // o = causal_attn(q, k, v)
  attn_kernel<<<dim3(32, 32), 64, 0, stream>>>(qkv, obuf);
  // x2 = x + o @ Wproj + bproj
  gemm_kernel<2><<<dim3(8, 32), 256, 0, stream>>>(obuf, WprojT, bproj, x, x2, 4096, 1024, 1024);
  // h2 = LN2(x2)
  ln_kernel<<<4096, 256, 0, stream>>>(x2, g2, be2, hbuf);
  // a1 = relu(h2 @ W1 + b1)
  gemm_kernel<1><<<dim3(32, 32), 256, 0, stream>>>(hbuf, W1T, b1, nullptr, a1, 4096, 4096, 1024);
  // out = x2 + a1 @ W2 + b2
  gemm_kernel<2><<<dim3(8, 32), 256, 0, stream>>>(a1, W2T, b2, x2, out, 4096, 1024, 4096);
}

// Round 3
// 344.992 us; speedup vs baseline: 5.1703x; 5.1703x over previous
//
#include <hip/hip_runtime.h>
#include <stdint.h>

typedef unsigned short u16;
typedef unsigned int u32;
typedef __attribute__((ext_vector_type(4))) float f32x4;
typedef __attribute__((ext_vector_type(8))) short s16x8;

__device__ __forceinline__ u16 f2bf(float f) {
  u32 u = __builtin_bit_cast(u32, f);
  u += 0x7fffu + ((u >> 16) & 1u);
  return (u16)(u >> 16);
}
__device__ __forceinline__ float bflo2f(u32 w) {
  return __builtin_bit_cast(float, w << 16);
}
__device__ __forceinline__ float bfhi2f(u32 w) {
  return __builtin_bit_cast(float, w & 0xffff0000u);
}
// 8-byte-aligned s16x8 load (2 x b64) for odd-stride LDS rows
__device__ __forceinline__ s16x8 ld_s16x8_a8(const u16* p) {
  union { uint2 d[2]; s16x8 v; } u;
  u.d[0] = *(const uint2*)p;
  u.d[1] = *(const uint2*)(p + 4);
  return u.v;
}

// ---------------------------------------------------------------------------
// Tiled transpose fp32 -> bf16: dst[(c)*dstStride + r] = src[r*Ccols + c]
// ---------------------------------------------------------------------------
__global__ __launch_bounds__(256) void transpose_f32_bf16(
    const float* __restrict__ src, u16* __restrict__ dst,
    int Ccols, long srcZ, long dstZ, int dstStride) {
  __shared__ float t[64][65];
  const float* s = src + (size_t)blockIdx.z * srcZ;
  u16* d = dst + (size_t)blockIdx.z * dstZ;
  const int r0 = blockIdx.y * 64, c0 = blockIdx.x * 64;
  const int tr = threadIdx.x >> 4, tc4 = (threadIdx.x & 15) * 4;
#pragma unroll
  for (int p = 0; p < 4; ++p) {
    int r = p * 16 + tr;
    float4 v = *(const float4*)(s + (size_t)(r0 + r) * Ccols + c0 + tc4);
    t[r][tc4 + 0] = v.x; t[r][tc4 + 1] = v.y;
    t[r][tc4 + 2] = v.z; t[r][tc4 + 3] = v.w;
  }
  __syncthreads();
#pragma unroll
  for (int p = 0; p < 4; ++p) {
    int c = p * 16 + tr;
    uint2 pk;
    pk.x = (u32)f2bf(t[tc4 + 0][c]) | ((u32)f2bf(t[tc4 + 1][c]) << 16);
    pk.y = (u32)f2bf(t[tc4 + 2][c]) | ((u32)f2bf(t[tc4 + 3][c]) << 16);
    *(uint2*)(d + (size_t)(c0 + c) * dstStride + r0 + tc4) = pk;
  }
}

// ---------------------------------------------------------------------------
// LayerNorm: one block per row of 1024 fp32; out bf16.
// ---------------------------------------------------------------------------
__global__ __launch_bounds__(256) void ln_kernel(
    const float* __restrict__ x, const float* __restrict__ g,
    const float* __restrict__ be, u16* __restrict__ out) {
  const int row = blockIdx.x, tid = threadIdx.x;
  const float* xr = x + (size_t)row * 1024;
  float4 v = *(const float4*)(xr + tid * 4);
  float s = v.x + v.y + v.z + v.w;
  float q = v.x * v.x + v.y * v.y + v.z * v.z + v.w * v.w;
#pragma unroll
  for (int off = 32; off > 0; off >>= 1) {
    s += __shfl_down(s, off);
    q += __shfl_down(q, off);
  }
  __shared__ float red[8];
  const int wid = tid >> 6, lane = tid & 63;
  if (lane == 0) { red[wid] = s; red[wid + 4] = q; }
  __syncthreads();
  s = red[0] + red[1] + red[2] + red[3];
  q = red[4] + red[5] + red[6] + red[7];
  const float mu = s * (1.f / 1024.f);
  const float var = q * (1.f / 1024.f) - mu * mu;
  const float rs = rsqrtf(var + 1e-5f);
  float4 gv = *(const float4*)(g + tid * 4);
  float4 bv = *(const float4*)(be + tid * 4);
  float o0 = (v.x - mu) * rs * gv.x + bv.x;
  float o1 = (v.y - mu) * rs * gv.y + bv.y;
  float o2 = (v.z - mu) * rs * gv.z + bv.z;
  float o3 = (v.w - mu) * rs * gv.w + bv.w;
  uint2 pk;
  pk.x = (u32)f2bf(o0) | ((u32)f2bf(o1) << 16);
  pk.y = (u32)f2bf(o2) | ((u32)f2bf(o3) << 16);
  *(uint2*)(out + (size_t)row * 1024 + tid * 4) = pk;
}

// ---------------------------------------------------------------------------
// GEMM: C[M,N] = A[M,K] @ BT[N,K]^T  (+ bias, relu, residual per EPI)
// ---------------------------------------------------------------------------
template <int EPI>
__global__ __launch_bounds__(256) void gemm_kernel(
    const u16* __restrict__ A, const u16* __restrict__ BT,
    const float* __restrict__ bias, const float* __restrict__ resid,
    void* __restrict__ out, int M, int N, int K) {
  __shared__ u16 sA[128][72];
  __shared__ u16 sB[128][72];
  const int tid = threadIdx.x;
  const int m0 = blockIdx.y * 128, n0 = blockIdx.x * 128;
  const int wid = tid >> 6, lane = tid & 63;
  const int wr = (wid >> 1) * 64, wc = (wid & 1) * 64;
  const int l15 = lane & 15, l4 = lane >> 4;
  f32x4 acc[4][4] = {};
  const int sr = tid >> 3, sc8 = (tid & 7) * 8;

  for (int k0 = 0; k0 < K; k0 += 64) {
    __syncthreads();
#pragma unroll
    for (int p = 0; p < 4; ++p) {
      int r = p * 32 + sr;
      *(uint4*)(&sA[r][sc8]) = *(const uint4*)(A + (size_t)(m0 + r) * K + k0 + sc8);
      *(uint4*)(&sB[r][sc8]) = *(const uint4*)(BT + (size_t)(n0 + r) * K + k0 + sc8);
    }
    __syncthreads();
#pragma unroll
    for (int kk = 0; kk < 64; kk += 32) {
      s16x8 af[4], bf[4];
#pragma unroll
      for (int m = 0; m < 4; ++m)
        af[m] = *(const s16x8*)(&sA[wr + m * 16 + l15][kk + l4 * 8]);
#pragma unroll
      for (int n = 0; n < 4; ++n)
        bf[n] = *(const s16x8*)(&sB[wc + n * 16 + l15][kk + l4 * 8]);
#pragma unroll
      for (int m = 0; m < 4; ++m)
#pragma unroll
        for (int n = 0; n < 4; ++n)
          acc[m][n] = __builtin_amdgcn_mfma_f32_16x16x32_bf16(af[m], bf[n], acc[m][n], 0, 0, 0);
    }
  }

#pragma unroll
  for (int m = 0; m < 4; ++m) {
#pragma unroll
    for (int n = 0; n < 4; ++n) {
      const int col = n0 + wc + n * 16 + l15;
      float bv = 0.f;
      if (EPI >= 1) bv = bias[col];
#pragma unroll
      for (int i = 0; i < 4; ++i) {
        const int row = m0 + wr + m * 16 + l4 * 4 + i;
        float v = acc[m][n][i];
        if (EPI >= 1) v += bv;
        if (EPI == 1) v = fmaxf(v, 0.f);
        if (EPI == 2) {
          v += resid[(size_t)row * N + col];
          ((float*)out)[(size_t)row * N + col] = v;
        } else {
          ((u16*)out)[(size_t)row * N + col] = f2bf(v);
        }
      }
    }
  }
}

// ---------------------------------------------------------------------------
// MFMA causal flash attention.
// qkv: [B*T][3072] bf16 (q|k|v sections, per-head cols h*64+d).
// out o: [B*T][1024] bf16.
// grid (32, B*H), block 256 (4 waves). Block qb handles q in [qb*64, qb*64+64);
// wave w handles 16 q-rows. KV tiles of 64 staged in LDS (K row-major, V^T).
// ---------------------------------------------------------------------------
__global__ __launch_bounds__(256) void attn_mfma_kernel(
    const u16* __restrict__ qkv, u16* __restrict__ o) {
  __shared__ u16 sK[64][72];    // [s][d], rows 144B (16B-aligned)
  __shared__ u16 sVt[64][68];   // [d][s], rows 136B (8B-aligned)
  __shared__ u16 sP[4][16][72]; // per-wave P strip [q][s]
  const int tid = threadIdx.x;
  const int qb = (int)gridDim.x - 1 - (int)blockIdx.x;  // heavy blocks first
  const int b = blockIdx.y >> 4, h = blockIdx.y & 15;
  const int w = tid >> 6, lane = tid & 63;
  const int l15 = lane & 15, g = lane >> 4;
  const float c = 0.125f * 1.4426950408889634f;  // scale * log2(e)

  // Q fragments (A-frag: row=l15, k = f*32 + g*8 + j)
  const size_t qrow = (size_t)(b * 2048 + qb * 64 + w * 16 + l15);
  s16x8 qf0 = *(const s16x8*)(qkv + qrow * 3072 + h * 64 + g * 8);
  s16x8 qf1 = *(const s16x8*)(qkv + qrow * 3072 + h * 64 + 32 + g * 8);

  f32x4 oacc[4] = {};  // O[q=4g+i][d = dt*16 + l15]
  float mrow[4] = {-1e30f, -1e30f, -1e30f, -1e30f};
  float lrow[4] = {0.f, 0.f, 0.f, 0.f};  // per-lane PARTIAL row sum (4 cols/tile);
                                         // reduced across the 16-lane group in epilogue

  // staging assignments (256 threads)
  const int ks_r = tid >> 2, ks_c = (tid & 3) * 16;  // K: 64 rows x 64 d
  const int vs_s = tid & 63, vs_d = (tid >> 6) * 8;  // V^T: lane=s contiguous

  const int nt = qb + 1;
  for (int t = 0; t < nt; ++t) {
    const int s0 = t * 64;
    __syncthreads();
    {  // K stage: coalesced row-major
      const u16* kp = qkv + (size_t)(b * 2048 + s0 + ks_r) * 3072 + 1024 + h * 64 + ks_c;
      *(uint4*)(&sK[ks_r][ks_c])     = *(const uint4*)kp;
      *(uint4*)(&sK[ks_r][ks_c + 8]) = *(const uint4*)(kp + 8);
    }
    {  // V stage transposed: ds_write_b16 lanes contiguous in s -> conflict-free
      const u16* vp = qkv + (size_t)(b * 2048 + s0 + vs_s) * 3072 + 2048 + h * 64;
      union { uint4 q4; u16 e[8]; } va, vb;
      va.q4 = *(const uint4*)(vp + vs_d);
      vb.q4 = *(const uint4*)(vp + vs_d + 32);
#pragma unroll
      for (int j = 0; j < 8; ++j) sVt[vs_d + j][vs_s] = va.e[j];
#pragma unroll
      for (int j = 0; j < 8; ++j) sVt[vs_d + 32 + j][vs_s] = vb.e[j];
    }
    __syncthreads();

    // QK^T: S[16 q][64 s] per wave; 4 s-tiles x 2 (K=32)
    f32x4 st[4];
#pragma unroll
    for (int n = 0; n < 4; ++n) {
      s16x8 k0 = *(const s16x8*)(&sK[n * 16 + l15][g * 8]);
      s16x8 k1 = *(const s16x8*)(&sK[n * 16 + l15][32 + g * 8]);
      f32x4 a = {};
      a = __builtin_amdgcn_mfma_f32_16x16x32_bf16(qf0, k0, a, 0, 0, 0);
      a = __builtin_amdgcn_mfma_f32_16x16x32_bf16(qf1, k1, a, 0, 0, 0);
      st[n] = a;
    }
    if (t == qb) {  // causal mask on diagonal tile
#pragma unroll
      for (int n = 0; n < 4; ++n)
#pragma unroll
        for (int i = 0; i < 4; ++i) {
          const int srel = n * 16 + l15, qrel = w * 16 + 4 * g + i;
          if (srel > qrel) st[n][i] = -1e30f;
        }
    }
    // row max (raw scores; scale folded into exp2 args)
    float pm[4];
#pragma unroll
    for (int i = 0; i < 4; ++i)
      pm[i] = fmaxf(fmaxf(st[0][i], st[1][i]), fmaxf(st[2][i], st[3][i]));
#pragma unroll
    for (int msk = 1; msk < 16; msk <<= 1)
#pragma unroll
      for (int i = 0; i < 4; ++i) pm[i] = fmaxf(pm[i], __shfl_xor(pm[i], msk));
    // online-softmax update (mrow/corr uniform across the 16-lane group)
    float corr[4];
#pragma unroll
    for (int i = 0; i < 4; ++i) {
      const float mnew = fmaxf(mrow[i], pm[i]);
      corr[i] = exp2f((mrow[i] - mnew) * c);
      mrow[i] = mnew;
      lrow[i] *= corr[i];
    }
#pragma unroll
    for (int dt = 0; dt < 4; ++dt)
#pragma unroll
      for (int i = 0; i < 4; ++i) oacc[dt][i] *= corr[i];
    float p[4][4];
#pragma unroll
    for (int n = 0; n < 4; ++n)
#pragma unroll
      for (int i = 0; i < 4; ++i) p[n][i] = exp2f((st[n][i] - mrow[i]) * c);
#pragma unroll
    for (int i = 0; i < 4; ++i)
      lrow[i] += (p[0][i] + p[1][i]) + (p[2][i] + p[3][i]);
    // P -> bf16 -> per-wave LDS strip (same-wave RAW; compiler emits lgkmcnt wait)
#pragma unroll
    for (int n = 0; n < 4; ++n)
#pragma unroll
      for (int i = 0; i < 4; ++i)
        sP[w][4 * g + i][n * 16 + l15] = f2bf(p[n][i]);
    // PV: O += P @ V ; A-frag = P rows, B-frag = V^T rows
    s16x8 pf0 = *(const s16x8*)(&sP[w][l15][g * 8]);
    s16x8 pf1 = *(const s16x8*)(&sP[w][l15][32 + g * 8]);
#pragma unroll
    for (int dt = 0; dt < 4; ++dt) {
      s16x8 vf0 = ld_s16x8_a8(&sVt[dt * 16 + l15][g * 8]);
      s16x8 vf1 = ld_s16x8_a8(&sVt[dt * 16 + l15][32 + g * 8]);
      oacc[dt] = __builtin_amdgcn_mfma_f32_16x16x32_bf16(pf0, vf0, oacc[dt], 0, 0, 0);
      oacc[dt] = __builtin_amdgcn_mfma_f32_16x16x32_bf16(pf1, vf1, oacc[dt], 0, 0, 0);
    }
  }

  // epilogue: REDUCE lrow across the 16-lane group (this was the round-2 NaN bug:
  // each lane only accumulated its 4 of 64 columns), then normalize, store bf16.
#pragma unroll
  for (int msk = 1; msk < 16; msk <<= 1)
#pragma unroll
    for (int i = 0; i < 4; ++i) lrow[i] += __shfl_xor(lrow[i], msk);
  float inv[4];
#pragma unroll
  for (int i = 0; i < 4; ++i) inv[i] = 1.f / lrow[i];
#pragma unroll
  for (int dt = 0; dt < 4; ++dt)
#pragma unroll
    for (int i = 0; i < 4; ++i) {
      const size_t row = (size_t)(b * 2048 + qb * 64 + w * 16 + 4 * g + i);
      o[row * 1024 + h * 64 + dt * 16 + l15] = f2bf(oacc[dt][i] * inv[i]);
    }
}

// ---------------------------------------------------------------------------
extern "C" void kernel_launch(void* const* d_in, const int* in_sizes, int n_in,
                              void* d_out, int out_size, void* d_ws, size_t ws_size,
                              hipStream_t stream) {
  const float* x     = (const float*)d_in[0];
  const float* Wq    = (const float*)d_in[1];
  const float* Wk    = (const float*)d_in[2];
  const float* Wv    = (const float*)d_in[3];
  const float* Wproj = (const float*)d_in[4];
  const float* bproj = (const float*)d_in[5];
  const float* W1    = (const float*)d_in[6];
  const float* b1    = (const float*)d_in[7];
  const float* W2    = (const float*)d_in[8];
  const float* b2    = (const float*)d_in[9];
  const float* g1    = (const float*)d_in[10];
  const float* be1   = (const float*)d_in[11];
  const float* g2    = (const float*)d_in[12];
  const float* be2   = (const float*)d_in[13];
  float* out = (float*)d_out;

  u16* WqkvT  = (u16*)d_ws;                    // [3072][1024] bf16
  u16* WprojT = WqkvT + (size_t)3072 * 1024;   // [1024][1024]
  u16* W1T    = WprojT + (size_t)1024 * 1024;  // [4096][1024]
  u16* W2T    = W1T + (size_t)4096 * 1024;     // [1024][4096]
  u16* hbuf   = W2T + (size_t)1024 * 4096;     // [4096][1024]
  u16* qkv    = hbuf + (size_t)4096 * 1024;    // [4096][3072]
  u16* obuf   = qkv + (size_t)4096 * 3072;     // [4096][1024]
  float* x2   = (float*)(obuf + (size_t)4096 * 1024);  // [4096][1024] fp32
  u16* a1     = (u16*)(x2 + (size_t)4096 * 1024);      // [4096][4096]

  transpose_f32_bf16<<<dim3(1, 16, 16), 256, 0, stream>>>(Wq, WqkvT,                      64, 65536, 65536, 1024);
  transpose_f32_bf16<<<dim3(1, 16, 16), 256, 0, stream>>>(Wk, WqkvT + (size_t)1024 * 1024, 64, 65536, 65536, 1024);
  transpose_f32_bf16<<<dim3(1, 16, 16), 256, 0, stream>>>(Wv, WqkvT + (size_t)2048 * 1024, 64, 65536, 65536, 1024);
  transpose_f32_bf16<<<dim3(16, 16, 1), 256, 0, stream>>>(Wproj, WprojT, 1024, 0, 0, 1024);
  transpose_f32_bf16<<<dim3(64, 16, 1), 256, 0, stream>>>(W1, W1T, 4096, 0, 0, 1024);
  transpose_f32_bf16<<<dim3(16, 64, 1), 256, 0, stream>>>(W2, W2T, 1024, 0, 0, 4096);

  ln_kernel<<<4096, 256, 0, stream>>>(x, g1, be1, hbuf);
  gemm_kernel<0><<<dim3(24, 32), 256, 0, stream>>>(hbuf, WqkvT, nullptr, nullptr, qkv, 4096, 3072, 1024);
  attn_mfma_kernel<<<dim3(32, 32), 256, 0, stream>>>(qkv, obuf);
  gemm_kernel<2><<<dim3(8, 32), 256, 0, stream>>>(obuf, WprojT, bproj, x, x2, 4096, 1024, 1024);
  ln_kernel<<<4096, 256, 0, stream>>>(x2, g2, be2, hbuf);
  gemm_kernel<1><<<dim3(32, 32), 256, 0, stream>>>(hbuf, W1T, b1, nullptr, a1, 4096, 4096, 1024);
  gemm_kernel<2><<<dim3(8, 32), 256, 0, stream>>>(a1, W2T, b2, x2, out, 4096, 1024, 4096);
}

// Round 7
// 299.784 us; speedup vs baseline: 5.9500x; 1.1508x over previous
//
#include <hip/hip_runtime.h>
#include <stdint.h>

// Round 7 == round 4 kernel resubmitted verbatim (3rd retry). Rounds 4-6 all
// died with UnresponsiveContainer on the SAME stale container before any
// compile/launch. The m97-GEMM + paired-attn change is still unmeasured;
// no code changes until we get one clean data point.

typedef unsigned short u16;
typedef unsigned int u32;
typedef __attribute__((ext_vector_type(4))) float f32x4;
typedef __attribute__((ext_vector_type(8))) short s16x8;

__device__ __forceinline__ u16 f2bf(float f) {
  u32 u = __builtin_bit_cast(u32, f);
  u += 0x7fffu + ((u >> 16) & 1u);
  return (u16)(u >> 16);
}
// 8-byte-aligned s16x8 load (2 x b64) for odd-stride LDS rows
__device__ __forceinline__ s16x8 ld_s16x8_a8(const u16* p) {
  union { uint2 d[2]; s16x8 v; } u;
  u.d[0] = *(const uint2*)p;
  u.d[1] = *(const uint2*)(p + 4);
  return u.v;
}
// async global->LDS, 16B per lane; lds dest must be wave-uniform base (lane*16 implicit)
__device__ __forceinline__ void gload16(const u16* g, u16* lds_base) {
  __builtin_amdgcn_global_load_lds(
      (const __attribute__((address_space(1))) void*)g,
      (__attribute__((address_space(3))) void*)lds_base, 16, 0, 0);
}

// ---------------------------------------------------------------------------
// Tiled transpose fp32 -> bf16: dst[(c)*dstStride + r] = src[r*Ccols + c]
// ---------------------------------------------------------------------------
__global__ __launch_bounds__(256) void transpose_f32_bf16(
    const float* __restrict__ src, u16* __restrict__ dst,
    int Ccols, long srcZ, long dstZ, int dstStride) {
  __shared__ float t[64][65];
  const float* s = src + (size_t)blockIdx.z * srcZ;
  u16* d = dst + (size_t)blockIdx.z * dstZ;
  const int r0 = blockIdx.y * 64, c0 = blockIdx.x * 64;
  const int tr = threadIdx.x >> 4, tc4 = (threadIdx.x & 15) * 4;
#pragma unroll
  for (int p = 0; p < 4; ++p) {
    int r = p * 16 + tr;
    float4 v = *(const float4*)(s + (size_t)(r0 + r) * Ccols + c0 + tc4);
    t[r][tc4 + 0] = v.x; t[r][tc4 + 1] = v.y;
    t[r][tc4 + 2] = v.z; t[r][tc4 + 3] = v.w;
  }
  __syncthreads();
#pragma unroll
  for (int p = 0; p < 4; ++p) {
    int c = p * 16 + tr;
    uint2 pk;
    pk.x = (u32)f2bf(t[tc4 + 0][c]) | ((u32)f2bf(t[tc4 + 1][c]) << 16);
    pk.y = (u32)f2bf(t[tc4 + 2][c]) | ((u32)f2bf(t[tc4 + 3][c]) << 16);
    *(uint2*)(d + (size_t)(c0 + c) * dstStride + r0 + tc4) = pk;
  }
}

// ---------------------------------------------------------------------------
// LayerNorm: one block per row of 1024 fp32; out bf16.
// ---------------------------------------------------------------------------
__global__ __launch_bounds__(256) void ln_kernel(
    const float* __restrict__ x, const float* __restrict__ g,
    const float* __restrict__ be, u16* __restrict__ out) {
  const int row = blockIdx.x, tid = threadIdx.x;
  const float* xr = x + (size_t)row * 1024;
  float4 v = *(const float4*)(xr + tid * 4);
  float s = v.x + v.y + v.z + v.w;
  float q = v.x * v.x + v.y * v.y + v.z * v.z + v.w * v.w;
#pragma unroll
  for (int off = 32; off > 0; off >>= 1) {
    s += __shfl_down(s, off);
    q += __shfl_down(q, off);
  }
  __shared__ float red[8];
  const int wid = tid >> 6, lane = tid & 63;
  if (lane == 0) { red[wid] = s; red[wid + 4] = q; }
  __syncthreads();
  s = red[0] + red[1] + red[2] + red[3];
  q = red[4] + red[5] + red[6] + red[7];
  const float mu = s * (1.f / 1024.f);
  const float var = q * (1.f / 1024.f) - mu * mu;
  const float rs = rsqrtf(var + 1e-5f);
  float4 gv = *(const float4*)(g + tid * 4);
  float4 bv = *(const float4*)(be + tid * 4);
  float o0 = (v.x - mu) * rs * gv.x + bv.x;
  float o1 = (v.y - mu) * rs * gv.y + bv.y;
  float o2 = (v.z - mu) * rs * gv.z + bv.z;
  float o3 = (v.w - mu) * rs * gv.w + bv.w;
  uint2 pk;
  pk.x = (u32)f2bf(o0) | ((u32)f2bf(o1) << 16);
  pk.y = (u32)f2bf(o2) | ((u32)f2bf(o3) << 16);
  *(uint2*)(out + (size_t)row * 1024 + tid * 4) = pk;
}

// ---------------------------------------------------------------------------
// GEMM: C[M,N] = A[M,K] @ BT[N,K]^T  (+ bias, relu, residual per EPI)
// EPI 0: -> bf16.  EPI 1: +bias, relu -> bf16.  EPI 2: +bias +resid -> fp32.
// BMx128 tile, BK=64, 256 threads (4 waves 2x2). m97 structure:
// global_load_lds width=16 into LINEAR LDS; XOR swizzle applied on the
// GLOBAL SOURCE address (rule #21) and the same XOR on ds_read (T2):
//   u16col ^= (row & 7) << 3   (rows are 128 B; 3-bit XOR over 16B slots)
// ---------------------------------------------------------------------------
template <int EPI, int BM>
__global__ __launch_bounds__(256) void gemm_kernel(
    const u16* __restrict__ A, const u16* __restrict__ BT,
    const float* __restrict__ bias, const float* __restrict__ resid,
    void* __restrict__ out, int M, int N, int K) {
  __shared__ u16 sA[BM][64];
  __shared__ u16 sB[128][64];
  const int tid = threadIdx.x;
  const int m0 = blockIdx.y * BM, n0 = blockIdx.x * 128;
  const int wid = tid >> 6, lane = tid & 63;
  const int wr = (wid >> 1) * (BM / 2), wc = (wid & 1) * 64;
  const int l15 = lane & 15, g = lane >> 4;
  constexpr int MR = BM / 32;
  f32x4 acc[MR][4] = {};
  // staging: lane covers 16B at [octet-row lr][16B-slot lane&7]; source col
  // pre-swizzled so LDS stays linear for global_load_lds (m104/m173/rule #21)
  const int lr = lane >> 3;
  const int cswz = ((lane & 7) * 8) ^ (lr << 3);  // u16 units

  for (int k0 = 0; k0 < K; k0 += 64) {
    __syncthreads();
#pragma unroll
    for (int p = 0; p < MR; ++p) {
      const int row = (p * 4 + wid) * 8 + lr;  // row & 7 == lr
      gload16(A + (size_t)(m0 + row) * K + k0 + cswz, &sA[(p * 4 + wid) * 8][0]);
    }
#pragma unroll
    for (int p = 0; p < 4; ++p) {
      const int row = (p * 4 + wid) * 8 + lr;
      gload16(BT + (size_t)(n0 + row) * K + k0 + cswz, &sB[(p * 4 + wid) * 8][0]);
    }
    __syncthreads();  // drains vmcnt(0) before any ds_read
#pragma unroll
    for (int kk = 0; kk < 64; kk += 32) {
      s16x8 af[MR], bf[4];
#pragma unroll
      for (int m = 0; m < MR; ++m) {
        const int R = wr + m * 16 + l15;  // R & 7 == l15 & 7
        af[m] = *(const s16x8*)(&sA[R][(kk + g * 8) ^ ((R & 7) << 3)]);
      }
#pragma unroll
      for (int n = 0; n < 4; ++n) {
        const int R = wc + n * 16 + l15;
        bf[n] = *(const s16x8*)(&sB[R][(kk + g * 8) ^ ((R & 7) << 3)]);
      }
#pragma unroll
      for (int m = 0; m < MR; ++m)
#pragma unroll
        for (int n = 0; n < 4; ++n)
          acc[m][n] = __builtin_amdgcn_mfma_f32_16x16x32_bf16(af[m], bf[n], acc[m][n], 0, 0, 0);
    }
  }

#pragma unroll
  for (int m = 0; m < MR; ++m) {
#pragma unroll
    for (int n = 0; n < 4; ++n) {
      const int col = n0 + wc + n * 16 + l15;
      float bv = 0.f;
      if (EPI >= 1) bv = bias[col];
#pragma unroll
      for (int i = 0; i < 4; ++i) {
        const int row = m0 + wr + m * 16 + g * 4 + i;
        float v = acc[m][n][i];
        if (EPI >= 1) v += bv;
        if (EPI == 1) v = fmaxf(v, 0.f);
        if (EPI == 2) {
          v += resid[(size_t)row * N + col];
          ((float*)out)[(size_t)row * N + col] = v;
        } else {
          ((u16*)out)[(size_t)row * N + col] = f2bf(v);
        }
      }
    }
  }
}

// ---------------------------------------------------------------------------
// MFMA causal flash attention, paired q-tiles for load balance.
// grid (16, B*H), block 256 (4 waves). Block bx handles q-tiles {31-bx, bx}
// (32-bx + bx+1 = 33 tiles of work for every block).
// ---------------------------------------------------------------------------
__global__ __launch_bounds__(256) void attn_mfma_kernel(
    const u16* __restrict__ qkv, u16* __restrict__ o) {
  __shared__ u16 sK[64][72];    // [s][d]
  __shared__ u16 sVt[64][68];   // [d][s]
  __shared__ u16 sP[4][16][72]; // per-wave P strip [q][s]
  const int tid = threadIdx.x;
  const int b = blockIdx.y >> 4, h = blockIdx.y & 15;
  const int w = tid >> 6, lane = tid & 63;
  const int l15 = lane & 15, g = lane >> 4;
  const float c = 0.125f * 1.4426950408889634f;  // scale * log2(e)
  const int ks_r = tid >> 2, ks_c = (tid & 3) * 16;
  const int vs_s = tid & 63, vs_d = (tid >> 6) * 8;

#pragma unroll 1
  for (int pass = 0; pass < 2; ++pass) {
    const int qb = pass == 0 ? (31 - (int)blockIdx.x) : (int)blockIdx.x;

    const size_t qrow = (size_t)(b * 2048 + qb * 64 + w * 16 + l15);
    s16x8 qf0 = *(const s16x8*)(qkv + qrow * 3072 + h * 64 + g * 8);
    s16x8 qf1 = *(const s16x8*)(qkv + qrow * 3072 + h * 64 + 32 + g * 8);

    f32x4 oacc[4] = {};  // O[q=4g+i][d = dt*16 + l15]
    float mrow[4] = {-1e30f, -1e30f, -1e30f, -1e30f};
    float lrow[4] = {0.f, 0.f, 0.f, 0.f};  // per-lane partial; reduced in epilogue

    const int nt = qb + 1;
    for (int t = 0; t < nt; ++t) {
      const int s0 = t * 64;
      __syncthreads();
      {  // K stage: coalesced row-major
        const u16* kp = qkv + (size_t)(b * 2048 + s0 + ks_r) * 3072 + 1024 + h * 64 + ks_c;
        *(uint4*)(&sK[ks_r][ks_c])     = *(const uint4*)kp;
        *(uint4*)(&sK[ks_r][ks_c + 8]) = *(const uint4*)(kp + 8);
      }
      {  // V stage transposed
        const u16* vp = qkv + (size_t)(b * 2048 + s0 + vs_s) * 3072 + 2048 + h * 64;
        union { uint4 q4; u16 e[8]; } va, vb;
        va.q4 = *(const uint4*)(vp + vs_d);
        vb.q4 = *(const uint4*)(vp + vs_d + 32);
#pragma unroll
        for (int j = 0; j < 8; ++j) sVt[vs_d + j][vs_s] = va.e[j];
#pragma unroll
        for (int j = 0; j < 8; ++j) sVt[vs_d + 32 + j][vs_s] = vb.e[j];
      }
      __syncthreads();

      // QK^T: S[16 q][64 s] per wave
      f32x4 st[4];
#pragma unroll
      for (int n = 0; n < 4; ++n) {
        s16x8 k0 = *(const s16x8*)(&sK[n * 16 + l15][g * 8]);
        s16x8 k1 = *(const s16x8*)(&sK[n * 16 + l15][32 + g * 8]);
        f32x4 a = {};
        a = __builtin_amdgcn_mfma_f32_16x16x32_bf16(qf0, k0, a, 0, 0, 0);
        a = __builtin_amdgcn_mfma_f32_16x16x32_bf16(qf1, k1, a, 0, 0, 0);
        st[n] = a;
      }
      if (t == qb) {  // causal mask on diagonal tile
#pragma unroll
        for (int n = 0; n < 4; ++n)
#pragma unroll
          for (int i = 0; i < 4; ++i) {
            const int srel = n * 16 + l15, qrel = w * 16 + 4 * g + i;
            if (srel > qrel) st[n][i] = -1e30f;
          }
      }
      float pm[4];
#pragma unroll
      for (int i = 0; i < 4; ++i)
        pm[i] = fmaxf(fmaxf(st[0][i], st[1][i]), fmaxf(st[2][i], st[3][i]));
#pragma unroll
      for (int msk = 1; msk < 16; msk <<= 1)
#pragma unroll
        for (int i = 0; i < 4; ++i) pm[i] = fmaxf(pm[i], __shfl_xor(pm[i], msk));
      float corr[4];
#pragma unroll
      for (int i = 0; i < 4; ++i) {
        const float mnew = fmaxf(mrow[i], pm[i]);
        corr[i] = exp2f((mrow[i] - mnew) * c);
        mrow[i] = mnew;
        lrow[i] *= corr[i];
      }
#pragma unroll
      for (int dt = 0; dt < 4; ++dt)
#pragma unroll
        for (int i = 0; i < 4; ++i) oacc[dt][i] *= corr[i];
      float p[4][4];
#pragma unroll
      for (int n = 0; n < 4; ++n)
#pragma unroll
        for (int i = 0; i < 4; ++i) p[n][i] = exp2f((st[n][i] - mrow[i]) * c);
#pragma unroll
      for (int i = 0; i < 4; ++i)
        lrow[i] += (p[0][i] + p[1][i]) + (p[2][i] + p[3][i]);
#pragma unroll
      for (int n = 0; n < 4; ++n)
#pragma unroll
        for (int i = 0; i < 4; ++i)
          sP[w][4 * g + i][n * 16 + l15] = f2bf(p[n][i]);
      s16x8 pf0 = *(const s16x8*)(&sP[w][l15][g * 8]);
      s16x8 pf1 = *(const s16x8*)(&sP[w][l15][32 + g * 8]);
#pragma unroll
      for (int dt = 0; dt < 4; ++dt) {
        s16x8 vf0 = ld_s16x8_a8(&sVt[dt * 16 + l15][g * 8]);
        s16x8 vf1 = ld_s16x8_a8(&sVt[dt * 16 + l15][32 + g * 8]);
        oacc[dt] = __builtin_amdgcn_mfma_f32_16x16x32_bf16(pf0, vf0, oacc[dt], 0, 0, 0);
        oacc[dt] = __builtin_amdgcn_mfma_f32_16x16x32_bf16(pf1, vf1, oacc[dt], 0, 0, 0);
      }
    }

    // epilogue: reduce lrow across the 16-lane group, normalize, store
#pragma unroll
    for (int msk = 1; msk < 16; msk <<= 1)
#pragma unroll
      for (int i = 0; i < 4; ++i) lrow[i] += __shfl_xor(lrow[i], msk);
    float inv[4];
#pragma unroll
    for (int i = 0; i < 4; ++i) inv[i] = 1.f / lrow[i];
#pragma unroll
    for (int dt = 0; dt < 4; ++dt)
#pragma unroll
      for (int i = 0; i < 4; ++i) {
        const size_t row = (size_t)(b * 2048 + qb * 64 + w * 16 + 4 * g + i);
        o[row * 1024 + h * 64 + dt * 16 + l15] = f2bf(oacc[dt][i] * inv[i]);
      }
  }
}

// ---------------------------------------------------------------------------
extern "C" void kernel_launch(void* const* d_in, const int* in_sizes, int n_in,
                              void* d_out, int out_size, void* d_ws, size_t ws_size,
                              hipStream_t stream) {
  const float* x     = (const float*)d_in[0];
  const float* Wq    = (const float*)d_in[1];
  const float* Wk    = (const float*)d_in[2];
  const float* Wv    = (const float*)d_in[3];
  const float* Wproj = (const float*)d_in[4];
  const float* bproj = (const float*)d_in[5];
  const float* W1    = (const float*)d_in[6];
  const float* b1    = (const float*)d_in[7];
  const float* W2    = (const float*)d_in[8];
  const float* b2    = (const float*)d_in[9];
  const float* g1    = (const float*)d_in[10];
  const float* be1   = (const float*)d_in[11];
  const float* g2    = (const float*)d_in[12];
  const float* be2   = (const float*)d_in[13];
  float* out = (float*)d_out;

  u16* WqkvT  = (u16*)d_ws;                    // [3072][1024] bf16
  u16* WprojT = WqkvT + (size_t)3072 * 1024;   // [1024][1024]
  u16* W1T    = WprojT + (size_t)1024 * 1024;  // [4096][1024]
  u16* W2T    = W1T + (size_t)4096 * 1024;     // [1024][4096]
  u16* hbuf   = W2T + (size_t)1024 * 4096;     // [4096][1024]
  u16* qkv    = hbuf + (size_t)4096 * 1024;    // [4096][3072]
  u16* obuf   = qkv + (size_t)4096 * 3072;     // [4096][1024]
  float* x2   = (float*)(obuf + (size_t)4096 * 1024);  // [4096][1024] fp32
  u16* a1     = (u16*)(x2 + (size_t)4096 * 1024);      // [4096][4096]

  transpose_f32_bf16<<<dim3(1, 16, 16), 256, 0, stream>>>(Wq, WqkvT,                      64, 65536, 65536, 1024);
  transpose_f32_bf16<<<dim3(1, 16, 16), 256, 0, stream>>>(Wk, WqkvT + (size_t)1024 * 1024, 64, 65536, 65536, 1024);
  transpose_f32_bf16<<<dim3(1, 16, 16), 256, 0, stream>>>(Wv, WqkvT + (size_t)2048 * 1024, 64, 65536, 65536, 1024);
  transpose_f32_bf16<<<dim3(16, 16, 1), 256, 0, stream>>>(Wproj, WprojT, 1024, 0, 0, 1024);
  transpose_f32_bf16<<<dim3(64, 16, 1), 256, 0, stream>>>(W1, W1T, 4096, 0, 0, 1024);
  transpose_f32_bf16<<<dim3(16, 64, 1), 256, 0, stream>>>(W2, W2T, 1024, 0, 0, 4096);

  ln_kernel<<<4096, 256, 0, stream>>>(x, g1, be1, hbuf);
  gemm_kernel<0, 128><<<dim3(24, 32), 256, 0, stream>>>(hbuf, WqkvT, nullptr, nullptr, qkv, 4096, 3072, 1024);
  attn_mfma_kernel<<<dim3(16, 32), 256, 0, stream>>>(qkv, obuf);
  gemm_kernel<2, 64><<<dim3(8, 64), 256, 0, stream>>>(obuf, WprojT, bproj, x, x2, 4096, 1024, 1024);
  ln_kernel<<<4096, 256, 0, stream>>>(x2, g2, be2, hbuf);
  gemm_kernel<1, 128><<<dim3(32, 32), 256, 0, stream>>>(hbuf, W1T, b1, nullptr, a1, 4096, 4096, 1024);
  gemm_kernel<2, 64><<<dim3(8, 64), 256, 0, stream>>>(a1, W2T, b2, x2, out, 4096, 1024, 4096);
}

// Round 8
// 279.749 us; speedup vs baseline: 6.3761x; 1.0716x over previous
//
#include <hip/hip_runtime.h>
#include <stdint.h>

// Round 8: attn gets T14 async-STAGE split (prefetch K/V tile t+1 into regs
// during tile t's compute; LDS write after the barrier). GEMMs/LN/transposes
// frozen from round 7 for attribution.

typedef unsigned short u16;
typedef unsigned int u32;
typedef __attribute__((ext_vector_type(4))) float f32x4;
typedef __attribute__((ext_vector_type(8))) short s16x8;

__device__ __forceinline__ u16 f2bf(float f) {
  u32 u = __builtin_bit_cast(u32, f);
  u += 0x7fffu + ((u >> 16) & 1u);
  return (u16)(u >> 16);
}
// 8-byte-aligned s16x8 load (2 x b64) for odd-stride LDS rows
__device__ __forceinline__ s16x8 ld_s16x8_a8(const u16* p) {
  union { uint2 d[2]; s16x8 v; } u;
  u.d[0] = *(const uint2*)p;
  u.d[1] = *(const uint2*)(p + 4);
  return u.v;
}
// async global->LDS, 16B per lane; lds dest must be wave-uniform base (lane*16 implicit)
__device__ __forceinline__ void gload16(const u16* g, u16* lds_base) {
  __builtin_amdgcn_global_load_lds(
      (const __attribute__((address_space(1))) void*)g,
      (__attribute__((address_space(3))) void*)lds_base, 16, 0, 0);
}

// ---------------------------------------------------------------------------
// Tiled transpose fp32 -> bf16: dst[(c)*dstStride + r] = src[r*Ccols + c]
// ---------------------------------------------------------------------------
__global__ __launch_bounds__(256) void transpose_f32_bf16(
    const float* __restrict__ src, u16* __restrict__ dst,
    int Ccols, long srcZ, long dstZ, int dstStride) {
  __shared__ float t[64][65];
  const float* s = src + (size_t)blockIdx.z * srcZ;
  u16* d = dst + (size_t)blockIdx.z * dstZ;
  const int r0 = blockIdx.y * 64, c0 = blockIdx.x * 64;
  const int tr = threadIdx.x >> 4, tc4 = (threadIdx.x & 15) * 4;
#pragma unroll
  for (int p = 0; p < 4; ++p) {
    int r = p * 16 + tr;
    float4 v = *(const float4*)(s + (size_t)(r0 + r) * Ccols + c0 + tc4);
    t[r][tc4 + 0] = v.x; t[r][tc4 + 1] = v.y;
    t[r][tc4 + 2] = v.z; t[r][tc4 + 3] = v.w;
  }
  __syncthreads();
#pragma unroll
  for (int p = 0; p < 4; ++p) {
    int c = p * 16 + tr;
    uint2 pk;
    pk.x = (u32)f2bf(t[tc4 + 0][c]) | ((u32)f2bf(t[tc4 + 1][c]) << 16);
    pk.y = (u32)f2bf(t[tc4 + 2][c]) | ((u32)f2bf(t[tc4 + 3][c]) << 16);
    *(uint2*)(d + (size_t)(c0 + c) * dstStride + r0 + tc4) = pk;
  }
}

// ---------------------------------------------------------------------------
// LayerNorm: one block per row of 1024 fp32; out bf16.
// ---------------------------------------------------------------------------
__global__ __launch_bounds__(256) void ln_kernel(
    const float* __restrict__ x, const float* __restrict__ g,
    const float* __restrict__ be, u16* __restrict__ out) {
  const int row = blockIdx.x, tid = threadIdx.x;
  const float* xr = x + (size_t)row * 1024;
  float4 v = *(const float4*)(xr + tid * 4);
  float s = v.x + v.y + v.z + v.w;
  float q = v.x * v.x + v.y * v.y + v.z * v.z + v.w * v.w;
#pragma unroll
  for (int off = 32; off > 0; off >>= 1) {
    s += __shfl_down(s, off);
    q += __shfl_down(q, off);
  }
  __shared__ float red[8];
  const int wid = tid >> 6, lane = tid & 63;
  if (lane == 0) { red[wid] = s; red[wid + 4] = q; }
  __syncthreads();
  s = red[0] + red[1] + red[2] + red[3];
  q = red[4] + red[5] + red[6] + red[7];
  const float mu = s * (1.f / 1024.f);
  const float var = q * (1.f / 1024.f) - mu * mu;
  const float rs = rsqrtf(var + 1e-5f);
  float4 gv = *(const float4*)(g + tid * 4);
  float4 bv = *(const float4*)(be + tid * 4);
  float o0 = (v.x - mu) * rs * gv.x + bv.x;
  float o1 = (v.y - mu) * rs * gv.y + bv.y;
  float o2 = (v.z - mu) * rs * gv.z + bv.z;
  float o3 = (v.w - mu) * rs * gv.w + bv.w;
  uint2 pk;
  pk.x = (u32)f2bf(o0) | ((u32)f2bf(o1) << 16);
  pk.y = (u32)f2bf(o2) | ((u32)f2bf(o3) << 16);
  *(uint2*)(out + (size_t)row * 1024 + tid * 4) = pk;
}

// ---------------------------------------------------------------------------
// GEMM: C[M,N] = A[M,K] @ BT[N,K]^T  (+ bias, relu, residual per EPI)
// EPI 0: -> bf16.  EPI 1: +bias, relu -> bf16.  EPI 2: +bias +resid -> fp32.
// BMx128 tile, BK=64, 256 threads (4 waves 2x2). m97 structure.
// ---------------------------------------------------------------------------
template <int EPI, int BM>
__global__ __launch_bounds__(256) void gemm_kernel(
    const u16* __restrict__ A, const u16* __restrict__ BT,
    const float* __restrict__ bias, const float* __restrict__ resid,
    void* __restrict__ out, int M, int N, int K) {
  __shared__ u16 sA[BM][64];
  __shared__ u16 sB[128][64];
  const int tid = threadIdx.x;
  const int m0 = blockIdx.y * BM, n0 = blockIdx.x * 128;
  const int wid = tid >> 6, lane = tid & 63;
  const int wr = (wid >> 1) * (BM / 2), wc = (wid & 1) * 64;
  const int l15 = lane & 15, g = lane >> 4;
  constexpr int MR = BM / 32;
  f32x4 acc[MR][4] = {};
  const int lr = lane >> 3;
  const int cswz = ((lane & 7) * 8) ^ (lr << 3);  // u16 units

  for (int k0 = 0; k0 < K; k0 += 64) {
    __syncthreads();
#pragma unroll
    for (int p = 0; p < MR; ++p) {
      const int row = (p * 4 + wid) * 8 + lr;  // row & 7 == lr
      gload16(A + (size_t)(m0 + row) * K + k0 + cswz, &sA[(p * 4 + wid) * 8][0]);
    }
#pragma unroll
    for (int p = 0; p < 4; ++p) {
      const int row = (p * 4 + wid) * 8 + lr;
      gload16(BT + (size_t)(n0 + row) * K + k0 + cswz, &sB[(p * 4 + wid) * 8][0]);
    }
    __syncthreads();  // drains vmcnt(0) before any ds_read
#pragma unroll
    for (int kk = 0; kk < 64; kk += 32) {
      s16x8 af[MR], bf[4];
#pragma unroll
      for (int m = 0; m < MR; ++m) {
        const int R = wr + m * 16 + l15;
        af[m] = *(const s16x8*)(&sA[R][(kk + g * 8) ^ ((R & 7) << 3)]);
      }
#pragma unroll
      for (int n = 0; n < 4; ++n) {
        const int R = wc + n * 16 + l15;
        bf[n] = *(const s16x8*)(&sB[R][(kk + g * 8) ^ ((R & 7) << 3)]);
      }
#pragma unroll
      for (int m = 0; m < MR; ++m)
#pragma unroll
        for (int n = 0; n < 4; ++n)
          acc[m][n] = __builtin_amdgcn_mfma_f32_16x16x32_bf16(af[m], bf[n], acc[m][n], 0, 0, 0);
    }
  }

#pragma unroll
  for (int m = 0; m < MR; ++m) {
#pragma unroll
    for (int n = 0; n < 4; ++n) {
      const int col = n0 + wc + n * 16 + l15;
      float bv = 0.f;
      if (EPI >= 1) bv = bias[col];
#pragma unroll
      for (int i = 0; i < 4; ++i) {
        const int row = m0 + wr + m * 16 + g * 4 + i;
        float v = acc[m][n][i];
        if (EPI >= 1) v += bv;
        if (EPI == 1) v = fmaxf(v, 0.f);
        if (EPI == 2) {
          v += resid[(size_t)row * N + col];
          ((float*)out)[(size_t)row * N + col] = v;
        } else {
          ((u16*)out)[(size_t)row * N + col] = f2bf(v);
        }
      }
    }
  }
}

// ---------------------------------------------------------------------------
// MFMA causal flash attention, paired q-tiles, T14 reg-prefetch staging.
// grid (16, B*H), block 256 (4 waves). Block bx handles q-tiles {31-bx, bx}.
// Per KV-tile: barrier -> write prefetched regs to LDS -> barrier ->
// issue loads for t+1 -> compute t (load latency hides under compute).
// ---------------------------------------------------------------------------
__global__ __launch_bounds__(256) void attn_mfma_kernel(
    const u16* __restrict__ qkv, u16* __restrict__ o) {
  __shared__ u16 sK[64][72];    // [s][d]
  __shared__ u16 sVt[64][68];   // [d][s]
  __shared__ u16 sP[4][16][72]; // per-wave P strip [q][s]
  const int tid = threadIdx.x;
  const int b = blockIdx.y >> 4, h = blockIdx.y & 15;
  const int w = tid >> 6, lane = tid & 63;
  const int l15 = lane & 15, g = lane >> 4;
  const float c = 0.125f * 1.4426950408889634f;  // scale * log2(e)
  const int ks_r = tid >> 2, ks_c = (tid & 3) * 16;
  const int vs_s = tid & 63, vs_d = (tid >> 6) * 8;
  const u16* kbase = qkv + (size_t)(b * 2048) * 3072 + 1024 + h * 64;
  const u16* vbase = kbase + 1024;

#pragma unroll 1
  for (int pass = 0; pass < 2; ++pass) {
    const int qb = pass == 0 ? (31 - (int)blockIdx.x) : (int)blockIdx.x;

    const size_t qrow = (size_t)(b * 2048 + qb * 64 + w * 16 + l15);
    s16x8 qf0 = *(const s16x8*)(qkv + qrow * 3072 + h * 64 + g * 8);
    s16x8 qf1 = *(const s16x8*)(qkv + qrow * 3072 + h * 64 + 32 + g * 8);

    f32x4 oacc[4] = {};  // O[q=4g+i][d = dt*16 + l15]
    float mrow[4] = {-1e30f, -1e30f, -1e30f, -1e30f};
    float lrow[4] = {0.f, 0.f, 0.f, 0.f};  // per-lane partial; reduced in epilogue

    const int nt = qb + 1;
    // prefetch tile 0 into regs (T14)
    uint4 kr0, kr1, vr0, vr1;
    {
      const u16* kp = kbase + (size_t)(ks_r)*3072 + ks_c;
      kr0 = *(const uint4*)kp; kr1 = *(const uint4*)(kp + 8);
      const u16* vp = vbase + (size_t)(vs_s)*3072 + vs_d;
      vr0 = *(const uint4*)vp; vr1 = *(const uint4*)(vp + 32);
    }
    for (int t = 0; t < nt; ++t) {
      __syncthreads();  // all waves done computing previous tile
      // write prefetched regs to LDS
      *(uint4*)(&sK[ks_r][ks_c]) = kr0;
      *(uint4*)(&sK[ks_r][ks_c + 8]) = kr1;
      {
        union { uint4 q4; u16 e[8]; } va, vb;
        va.q4 = vr0; vb.q4 = vr1;
#pragma unroll
        for (int j = 0; j < 8; ++j) sVt[vs_d + j][vs_s] = va.e[j];
#pragma unroll
        for (int j = 0; j < 8; ++j) sVt[vs_d + 32 + j][vs_s] = vb.e[j];
      }
      __syncthreads();
      // issue next tile's global loads; latency hides under compute below
      if (t + 1 < nt) {
        const u16* kp = kbase + (size_t)((t + 1) * 64 + ks_r) * 3072 + ks_c;
        kr0 = *(const uint4*)kp; kr1 = *(const uint4*)(kp + 8);
        const u16* vp = vbase + (size_t)((t + 1) * 64 + vs_s) * 3072 + vs_d;
        vr0 = *(const uint4*)vp; vr1 = *(const uint4*)(vp + 32);
      }

      // QK^T: S[16 q][64 s] per wave
      f32x4 st[4];
#pragma unroll
      for (int n = 0; n < 4; ++n) {
        s16x8 k0 = *(const s16x8*)(&sK[n * 16 + l15][g * 8]);
        s16x8 k1 = *(const s16x8*)(&sK[n * 16 + l15][32 + g * 8]);
        f32x4 a = {};
        a = __builtin_amdgcn_mfma_f32_16x16x32_bf16(qf0, k0, a, 0, 0, 0);
        a = __builtin_amdgcn_mfma_f32_16x16x32_bf16(qf1, k1, a, 0, 0, 0);
        st[n] = a;
      }
      if (t == qb) {  // causal mask on diagonal tile
#pragma unroll
        for (int n = 0; n < 4; ++n)
#pragma unroll
          for (int i = 0; i < 4; ++i) {
            const int srel = n * 16 + l15, qrel = w * 16 + 4 * g + i;
            if (srel > qrel) st[n][i] = -1e30f;
          }
      }
      float pm[4];
#pragma unroll
      for (int i = 0; i < 4; ++i)
        pm[i] = fmaxf(fmaxf(st[0][i], st[1][i]), fmaxf(st[2][i], st[3][i]));
#pragma unroll
      for (int msk = 1; msk < 16; msk <<= 1)
#pragma unroll
        for (int i = 0; i < 4; ++i) pm[i] = fmaxf(pm[i], __shfl_xor(pm[i], msk));
      float corr[4];
#pragma unroll
      for (int i = 0; i < 4; ++i) {
        const float mnew = fmaxf(mrow[i], pm[i]);
        corr[i] = exp2f((mrow[i] - mnew) * c);
        mrow[i] = mnew;
        lrow[i] *= corr[i];
      }
#pragma unroll
      for (int dt = 0; dt < 4; ++dt)
#pragma unroll
        for (int i = 0; i < 4; ++i) oacc[dt][i] *= corr[i];
      float p[4][4];
#pragma unroll
      for (int n = 0; n < 4; ++n)
#pragma unroll
        for (int i = 0; i < 4; ++i) p[n][i] = exp2f((st[n][i] - mrow[i]) * c);
#pragma unroll
      for (int i = 0; i < 4; ++i)
        lrow[i] += (p[0][i] + p[1][i]) + (p[2][i] + p[3][i]);
#pragma unroll
      for (int n = 0; n < 4; ++n)
#pragma unroll
        for (int i = 0; i < 4; ++i)
          sP[w][4 * g + i][n * 16 + l15] = f2bf(p[n][i]);
      s16x8 pf0 = *(const s16x8*)(&sP[w][l15][g * 8]);
      s16x8 pf1 = *(const s16x8*)(&sP[w][l15][32 + g * 8]);
#pragma unroll
      for (int dt = 0; dt < 4; ++dt) {
        s16x8 vf0 = ld_s16x8_a8(&sVt[dt * 16 + l15][g * 8]);
        s16x8 vf1 = ld_s16x8_a8(&sVt[dt * 16 + l15][32 + g * 8]);
        oacc[dt] = __builtin_amdgcn_mfma_f32_16x16x32_bf16(pf0, vf0, oacc[dt], 0, 0, 0);
        oacc[dt] = __builtin_amdgcn_mfma_f32_16x16x32_bf16(pf1, vf1, oacc[dt], 0, 0, 0);
      }
    }

    // epilogue: reduce lrow across the 16-lane group, normalize, store
#pragma unroll
    for (int msk = 1; msk < 16; msk <<= 1)
#pragma unroll
      for (int i = 0; i < 4; ++i) lrow[i] += __shfl_xor(lrow[i], msk);
    float inv[4];
#pragma unroll
    for (int i = 0; i < 4; ++i) inv[i] = 1.f / lrow[i];
#pragma unroll
    for (int dt = 0; dt < 4; ++dt)
#pragma unroll
      for (int i = 0; i < 4; ++i) {
        const size_t row = (size_t)(b * 2048 + qb * 64 + w * 16 + 4 * g + i);
        o[row * 1024 + h * 64 + dt * 16 + l15] = f2bf(oacc[dt][i] * inv[i]);
      }
  }
}

// ---------------------------------------------------------------------------
extern "C" void kernel_launch(void* const* d_in, const int* in_sizes, int n_in,
                              void* d_out, int out_size, void* d_ws, size_t ws_size,
                              hipStream_t stream) {
  const float* x     = (const float*)d_in[0];
  const float* Wq    = (const float*)d_in[1];
  const float* Wk    = (const float*)d_in[2];
  const float* Wv    = (const float*)d_in[3];
  const float* Wproj = (const float*)d_in[4];
  const float* bproj = (const float*)d_in[5];
  const float* W1    = (const float*)d_in[6];
  const float* b1    = (const float*)d_in[7];
  const float* W2    = (const float*)d_in[8];
  const float* b2    = (const float*)d_in[9];
  const float* g1    = (const float*)d_in[10];
  const float* be1   = (const float*)d_in[11];
  const float* g2    = (const float*)d_in[12];
  const float* be2   = (const float*)d_in[13];
  float* out = (float*)d_out;

  u16* WqkvT  = (u16*)d_ws;                    // [3072][1024] bf16
  u16* WprojT = WqkvT + (size_t)3072 * 1024;   // [1024][1024]
  u16* W1T    = WprojT + (size_t)1024 * 1024;  // [4096][1024]
  u16* W2T    = W1T + (size_t)4096 * 1024;     // [1024][4096]
  u16* hbuf   = W2T + (size_t)1024 * 4096;     // [4096][1024]
  u16* qkv    = hbuf + (size_t)4096 * 1024;    // [4096][3072]
  u16* obuf   = qkv + (size_t)4096 * 3072;     // [4096][1024]
  float* x2   = (float*)(obuf + (size_t)4096 * 1024);  // [4096][1024] fp32
  u16* a1     = (u16*)(x2 + (size_t)4096 * 1024);      // [4096][4096]

  transpose_f32_bf16<<<dim3(1, 16, 16), 256, 0, stream>>>(Wq, WqkvT,                      64, 65536, 65536, 1024);
  transpose_f32_bf16<<<dim3(1, 16, 16), 256, 0, stream>>>(Wk, WqkvT + (size_t)1024 * 1024, 64, 65536, 65536, 1024);
  transpose_f32_bf16<<<dim3(1, 16, 16), 256, 0, stream>>>(Wv, WqkvT + (size_t)2048 * 1024, 64, 65536, 65536, 1024);
  transpose_f32_bf16<<<dim3(16, 16, 1), 256, 0, stream>>>(Wproj, WprojT, 1024, 0, 0, 1024);
  transpose_f32_bf16<<<dim3(64, 16, 1), 256, 0, stream>>>(W1, W1T, 4096, 0, 0, 1024);
  transpose_f32_bf16<<<dim3(16, 64, 1), 256, 0, stream>>>(W2, W2T, 1024, 0, 0, 4096);

  ln_kernel<<<4096, 256, 0, stream>>>(x, g1, be1, hbuf);
  gemm_kernel<0, 128><<<dim3(24, 32), 256, 0, stream>>>(hbuf, WqkvT, nullptr, nullptr, qkv, 4096, 3072, 1024);
  attn_mfma_kernel<<<dim3(16, 32), 256, 0, stream>>>(qkv, obuf);
  gemm_kernel<2, 64><<<dim3(8, 64), 256, 0, stream>>>(obuf, WprojT, bproj, x, x2, 4096, 1024, 1024);
  ln_kernel<<<4096, 256, 0, stream>>>(x2, g2, be2, hbuf);
  gemm_kernel<1, 128><<<dim3(32, 32), 256, 0, stream>>>(hbuf, W1T, b1, nullptr, a1, 4096, 4096, 1024);
  gemm_kernel<2, 64><<<dim3(8, 64), 256, 0, stream>>>(a1, W2T, b2, x2, out, 4096, 1024, 4096);
}